// Round 2
// baseline (422.557 us; speedup 1.0000x reference)
//
#include <hip/hip_runtime.h>

#define ESN_B 16
#define ESN_D 2048
#define ESN_L 512

typedef __attribute__((ext_vector_type(8))) short bf16x8;
typedef __attribute__((ext_vector_type(4))) float f32x4;

typedef unsigned int __attribute__((address_space(1))) as1_u32;
typedef unsigned int __attribute__((address_space(3))) as3_u32;

__device__ __forceinline__ void gl2lds16(const void* g, void* l) {
  // async global->LDS, 16B per lane; LDS dest = wave-uniform base + lane*16
  __builtin_amdgcn_global_load_lds((const as1_u32*)g, (as3_u32*)l, 16, 0, 0);
}

__device__ __forceinline__ unsigned short f2bf_rne(float x) {
  unsigned int u = __float_as_uint(x);
  unsigned int r = (u + 0x7FFFu + ((u >> 16) & 1u)) >> 16;
  return (unsigned short)r;
}
__device__ __forceinline__ float bf2f(unsigned short h) {
  return __uint_as_float(((unsigned int)h) << 16);
}
__device__ __forceinline__ void split2(float x, unsigned short& h, unsigned short& l) {
  h = f2bf_rne(x);
  l = f2bf_rne(x - bf2f(h));
}

// ---------- split w_in (fp32 [D][D]) into hi/lo bf16, same layout ----------
__global__ __launch_bounds__(256) void k_split_w(const float* __restrict__ w,
                                                 unsigned short* __restrict__ wh,
                                                 unsigned short* __restrict__ wl) {
  int i = blockIdx.x * 256 + threadIdx.x;  // grid sized exactly: D*D/4 elements
  float4 v = ((const float4*)w)[i];
  ushort4 h, l;
  split2(v.x, h.x, l.x);
  split2(v.y, h.y, l.y);
  split2(v.z, h.z, l.z);
  split2(v.w, h.w, l.w);
  ((ushort4*)wh)[i] = h;
  ((ushort4*)wl)[i] = l;
}

// ---------- split + transpose u: [B][D][L] fp32 -> [B][L][D] bf16 hi/lo ----------
__global__ __launch_bounds__(256) void k_split_transpose_u(const float* __restrict__ u,
                                                           unsigned short* __restrict__ uh,
                                                           unsigned short* __restrict__ ul) {
  __shared__ float tile[64][65];
  const int b = blockIdx.z;
  const int h0 = blockIdx.y * 64;
  const int k0 = blockIdx.x * 64;
  const int t = threadIdx.x;
  const int r = t >> 4;         // 0..15
  const int c4 = (t & 15) * 4;  // 0..60
#pragma unroll
  for (int i = 0; i < 4; ++i) {
    int hh = r + i * 16;
    float4 v = *(const float4*)&u[((size_t)b * ESN_D + h0 + hh) * ESN_L + k0 + c4];
    tile[hh][c4 + 0] = v.x;
    tile[hh][c4 + 1] = v.y;
    tile[hh][c4 + 2] = v.z;
    tile[hh][c4 + 3] = v.w;
  }
  __syncthreads();
#pragma unroll
  for (int i = 0; i < 4; ++i) {
    int kk = r + i * 16;
    float x0 = tile[c4 + 0][kk], x1 = tile[c4 + 1][kk];
    float x2 = tile[c4 + 2][kk], x3 = tile[c4 + 3][kk];
    ushort4 h, l;
    split2(x0, h.x, l.x);
    split2(x1, h.y, l.y);
    split2(x2, h.z, l.z);
    split2(x3, h.w, l.w);
    size_t o = ((size_t)b * ESN_L + k0 + kk) * ESN_D + h0 + c4;
    *(ushort4*)&uh[o] = h;
    *(ushort4*)&ul[o] = l;
  }
}

// ---------- main GEMM: Z[b,p,n] = sum_h W[p,h] * Ut[b,n,h], hi/lo 3-product ----------
// 128x128 tile, BK=32, 4 waves (2x2), each wave 64x64 via 4x4 frags of 16x16x32.
// Staging via global_load_lds width=16 into LINEAR [128][32] tiles (row stride
// 64B => fragment ds_read_b128 is bank-balanced: 8 distinct addrs on every
// bank = the 8-cycle minimum for 1024B; no pad/swizzle needed or allowed).
__global__ __launch_bounds__(256, 2) void k_esn_gemm(const unsigned short* __restrict__ Wh,
                                                     const unsigned short* __restrict__ Wl,
                                                     const unsigned short* __restrict__ Uh,
                                                     const unsigned short* __restrict__ Ul,
                                                     float* __restrict__ Z) {
  __shared__ __align__(16) unsigned short sm[4][128][32];  // Ah, Al, Bh, Bl (8KB each)

  const int b = blockIdx.z;
  const int p0 = blockIdx.y * 128;
  const int n0 = blockIdx.x * 128;
  const int t = threadIdx.x;
  const int lane = t & 63;
  const int wid = t >> 6;
  const int wm = (wid >> 1) * 64;  // wave row offset in tile
  const int wn = (wid & 1) * 64;   // wave col offset in tile
  const int l15 = lane & 15;
  const int lg8 = (lane >> 4) * 8;

  // staging: wave wid stages 1KB chunks {2wid, 2wid+1} of each matrix.
  // chunk q covers rows q*16..q*16+15; lane l -> row q*16+(l>>2), ushort col (l&3)*8
  const int q0 = wid * 2;
  const int r0 = q0 * 16 + (lane >> 2);
  const int r1 = r0 + 16;
  const int sc = (lane & 3) * 8;

  const unsigned short* wh0 = Wh + (size_t)(p0 + r0) * ESN_D + sc;
  const unsigned short* wh1 = Wh + (size_t)(p0 + r1) * ESN_D + sc;
  const unsigned short* wl0 = Wl + (size_t)(p0 + r0) * ESN_D + sc;
  const unsigned short* wl1 = Wl + (size_t)(p0 + r1) * ESN_D + sc;
  const unsigned short* uh0 = Uh + ((size_t)b * ESN_L + n0 + r0) * ESN_D + sc;
  const unsigned short* uh1 = Uh + ((size_t)b * ESN_L + n0 + r1) * ESN_D + sc;
  const unsigned short* ul0 = Ul + ((size_t)b * ESN_L + n0 + r0) * ESN_D + sc;
  const unsigned short* ul1 = Ul + ((size_t)b * ESN_L + n0 + r1) * ESN_D + sc;

  unsigned short* dAh0 = &sm[0][q0 * 16][0];
  unsigned short* dAh1 = &sm[0][q0 * 16 + 16][0];
  unsigned short* dAl0 = &sm[1][q0 * 16][0];
  unsigned short* dAl1 = &sm[1][q0 * 16 + 16][0];
  unsigned short* dBh0 = &sm[2][q0 * 16][0];
  unsigned short* dBh1 = &sm[2][q0 * 16 + 16][0];
  unsigned short* dBl0 = &sm[3][q0 * 16][0];
  unsigned short* dBl1 = &sm[3][q0 * 16 + 16][0];

  f32x4 acc[4][4] = {};

  for (int h0 = 0; h0 < ESN_D; h0 += 32) {
    __syncthreads();  // all consumers of the previous tile are done
    gl2lds16(wh0 + h0, dAh0);
    gl2lds16(wh1 + h0, dAh1);
    gl2lds16(wl0 + h0, dAl0);
    gl2lds16(wl1 + h0, dAl1);
    gl2lds16(uh0 + h0, dBh0);
    gl2lds16(uh1 + h0, dBh1);
    gl2lds16(ul0 + h0, dBl0);
    gl2lds16(ul1 + h0, dBl1);
    __syncthreads();  // implicit vmcnt(0) drain before s_barrier -> tile visible

    bf16x8 ah[4], al[4], bh[4], bl[4];
#pragma unroll
    for (int i = 0; i < 4; ++i) {
      ah[i] = *(const bf16x8*)&sm[0][wm + i * 16 + l15][lg8];
      al[i] = *(const bf16x8*)&sm[1][wm + i * 16 + l15][lg8];
      bh[i] = *(const bf16x8*)&sm[2][wn + i * 16 + l15][lg8];
      bl[i] = *(const bf16x8*)&sm[3][wn + i * 16 + l15][lg8];
    }
#pragma unroll
    for (int i = 0; i < 4; ++i)
#pragma unroll
      for (int j = 0; j < 4; ++j) {
        acc[i][j] = __builtin_amdgcn_mfma_f32_16x16x32_bf16(ah[i], bh[j], acc[i][j], 0, 0, 0);
        acc[i][j] = __builtin_amdgcn_mfma_f32_16x16x32_bf16(ah[i], bl[j], acc[i][j], 0, 0, 0);
        acc[i][j] = __builtin_amdgcn_mfma_f32_16x16x32_bf16(al[i], bh[j], acc[i][j], 0, 0, 0);
      }
  }

// C/D layout (m89-verified): col = lane&15, row = (lane>>4)*4 + reg
#pragma unroll
  for (int i = 0; i < 4; ++i)
#pragma unroll
    for (int j = 0; j < 4; ++j) {
      const int rp = p0 + wm + i * 16 + (lane >> 4) * 4;
      const int cn = n0 + wn + j * 16 + l15;
      float* zp = &Z[((size_t)b * ESN_D + rp) * ESN_L + cn];
#pragma unroll
      for (int r = 0; r < 4; ++r) zp[(size_t)r * ESN_L] = acc[i][j][r];
    }
}

// ---------- fallback fp32 GEMM (no workspace needed): Z[b,p,n] = sum_h W[p,h]*U[b,h,n] ----------
__global__ __launch_bounds__(256) void k_gemm_f32(const float* __restrict__ W,
                                                  const float* __restrict__ U,
                                                  float* __restrict__ Z) {
  __shared__ float sA[16][65];  // [h][p]
  __shared__ float sB[16][65];  // [h][n]
  const int b = blockIdx.z, p0 = blockIdx.y * 64, n0 = blockIdx.x * 64;
  const int t = threadIdx.x;
  const int tx = t & 15, ty = t >> 4;
  float c[4][4] = {};
  for (int h0 = 0; h0 < ESN_D; h0 += 16) {
    __syncthreads();
#pragma unroll
    for (int i = 0; i < 4; ++i) {
      int e = t + i * 256;
      int ra = e >> 4, ca = e & 15;
      sA[ca][ra] = W[(size_t)(p0 + ra) * ESN_D + h0 + ca];
      int rb = e >> 6, cb = e & 63;
      sB[rb][cb] = U[((size_t)b * ESN_D + h0 + rb) * ESN_L + n0 + cb];
    }
    __syncthreads();
#pragma unroll
    for (int kk = 0; kk < 16; ++kk) {
      float a[4], bb[4];
#pragma unroll
      for (int i = 0; i < 4; ++i) a[i] = sA[kk][ty * 4 + i];
#pragma unroll
      for (int j = 0; j < 4; ++j) bb[j] = sB[kk][tx * 4 + j];
#pragma unroll
      for (int i = 0; i < 4; ++i)
#pragma unroll
        for (int j = 0; j < 4; ++j) c[i][j] += a[i] * bb[j];
    }
  }
#pragma unroll
  for (int i = 0; i < 4; ++i)
#pragma unroll
    for (int j = 0; j < 4; ++j)
      Z[((size_t)b * ESN_D + p0 + ty * 4 + i) * ESN_L + n0 + tx * 4 + j] = c[i][j];
}

// ---------- elementwise leaky-integrator scan, in place on Z (lr = 1) ----------
// tanh(x) = 1 - 2/(e^{2x}+1): saturates cleanly to +/-1 for |x| large (inf-safe),
// ~1e-6 abs error via v_exp_f32 — far below the GEMM's ~1e-4 split residual.
__device__ __forceinline__ float fast_tanh(float x) {
  float e = __expf(2.0f * x);
  return 1.0f - __fdividef(2.0f, e + 1.0f);
}

__global__ __launch_bounds__(256) void k_scan(float* __restrict__ Z,
                                              const float* __restrict__ w_hh,
                                              const float* __restrict__ bias) {
  const int gid = blockIdx.x * 256 + threadIdx.x;  // B*D threads
  const int p = gid & (ESN_D - 1);
  const float dg = w_hh[(size_t)p * (ESN_D + 1)];  // diagonal element w_hh[p][p]
  const float bs = bias[p];
  float4* row = (float4*)(Z + (size_t)gid * ESN_L);
  float x = 0.f;
  float4 cur = row[0];
#pragma unroll 1
  for (int q = 0; q < ESN_L / 4; ++q) {
    float4 nxt;
    if (q + 1 < ESN_L / 4) nxt = row[q + 1];  // prefetch next before tanh chain
    float x0 = fast_tanh(cur.x + dg * x + bs);
    float x1 = fast_tanh(cur.y + dg * x0 + bs);
    float x2 = fast_tanh(cur.z + dg * x1 + bs);
    float x3 = fast_tanh(cur.w + dg * x2 + bs);
    row[q] = make_float4(x0, x1, x2, x3);
    x = x3;
    cur = nxt;
  }
}

extern "C" void kernel_launch(void* const* d_in, const int* in_sizes, int n_in, void* d_out,
                              int out_size, void* d_ws, size_t ws_size, hipStream_t stream) {
  const float* u = (const float*)d_in[0];
  const float* w_in = (const float*)d_in[1];
  const float* w_hh = (const float*)d_in[2];
  const float* bias = (const float*)d_in[3];
  float* Z = (float*)d_out;  // Z computed here, then scan updates in place

  const size_t nW = (size_t)ESN_D * ESN_D;
  const size_t nU = (size_t)ESN_B * ESN_L * ESN_D;
  const size_t needed = (2 * nW + 2 * nU) * sizeof(unsigned short);  // 80 MiB

  if (ws_size >= needed) {
    unsigned short* Wh = (unsigned short*)d_ws;
    unsigned short* Wl = Wh + nW;
    unsigned short* Uh = Wl + nW;
    unsigned short* Ul = Uh + nU;
    k_split_w<<<(int)(nW / 4 / 256), 256, 0, stream>>>(w_in, Wh, Wl);
    k_split_transpose_u<<<dim3(ESN_L / 64, ESN_D / 64, ESN_B), 256, 0, stream>>>(u, Uh, Ul);
    k_esn_gemm<<<dim3(ESN_L / 128, ESN_D / 128, ESN_B), 256, 0, stream>>>(Wh, Wl, Uh, Ul, Z);
  } else {
    k_gemm_f32<<<dim3(ESN_L / 64, ESN_D / 64, ESN_B), 256, 0, stream>>>(w_in, u, Z);
  }
  k_scan<<<(ESN_B * ESN_D) / 256, 256, 0, stream>>>(Z, w_hh, bias);
}

// Round 3
// 403.752 us; speedup vs baseline: 1.0466x; 1.0466x over previous
//
#include <hip/hip_runtime.h>

#define ESN_B 16
#define ESN_D 2048
#define ESN_L 512

typedef __attribute__((ext_vector_type(8))) short bf16x8;
typedef __attribute__((ext_vector_type(4))) float f32x4;

typedef unsigned int __attribute__((address_space(1))) as1_u32;
typedef unsigned int __attribute__((address_space(3))) as3_u32;

__device__ __forceinline__ void gl2lds16(const void* g, void* l) {
  // async global->LDS, 16B per lane; LDS dest = wave-uniform base + lane*16
  __builtin_amdgcn_global_load_lds((const as1_u32*)g, (as3_u32*)l, 16, 0, 0);
}

__device__ __forceinline__ unsigned short f2bf_rne(float x) {
  unsigned int u = __float_as_uint(x);
  unsigned int r = (u + 0x7FFFu + ((u >> 16) & 1u)) >> 16;
  return (unsigned short)r;
}
__device__ __forceinline__ float bf2f(unsigned short h) {
  return __uint_as_float(((unsigned int)h) << 16);
}
__device__ __forceinline__ void split2(float x, unsigned short& h, unsigned short& l) {
  h = f2bf_rne(x);
  l = f2bf_rne(x - bf2f(h));
}

// ---------- split w_in (fp32 [D][D]) into hi/lo bf16, same layout ----------
__global__ __launch_bounds__(256) void k_split_w(const float* __restrict__ w,
                                                 unsigned short* __restrict__ wh,
                                                 unsigned short* __restrict__ wl) {
  int i = blockIdx.x * 256 + threadIdx.x;  // grid sized exactly: D*D/4 elements
  float4 v = ((const float4*)w)[i];
  ushort4 h, l;
  split2(v.x, h.x, l.x);
  split2(v.y, h.y, l.y);
  split2(v.z, h.z, l.z);
  split2(v.w, h.w, l.w);
  ((ushort4*)wh)[i] = h;
  ((ushort4*)wl)[i] = l;
}

// ---------- split + transpose u: [B][D][L] fp32 -> [B][L][D] bf16 hi/lo ----------
__global__ __launch_bounds__(256) void k_split_transpose_u(const float* __restrict__ u,
                                                           unsigned short* __restrict__ uh,
                                                           unsigned short* __restrict__ ul) {
  __shared__ float tile[64][65];
  const int b = blockIdx.z;
  const int h0 = blockIdx.y * 64;
  const int k0 = blockIdx.x * 64;
  const int t = threadIdx.x;
  const int r = t >> 4;         // 0..15
  const int c4 = (t & 15) * 4;  // 0..60
#pragma unroll
  for (int i = 0; i < 4; ++i) {
    int hh = r + i * 16;
    float4 v = *(const float4*)&u[((size_t)b * ESN_D + h0 + hh) * ESN_L + k0 + c4];
    tile[hh][c4 + 0] = v.x;
    tile[hh][c4 + 1] = v.y;
    tile[hh][c4 + 2] = v.z;
    tile[hh][c4 + 3] = v.w;
  }
  __syncthreads();
#pragma unroll
  for (int i = 0; i < 4; ++i) {
    int kk = r + i * 16;
    float x0 = tile[c4 + 0][kk], x1 = tile[c4 + 1][kk];
    float x2 = tile[c4 + 2][kk], x3 = tile[c4 + 3][kk];
    ushort4 h, l;
    split2(x0, h.x, l.x);
    split2(x1, h.y, l.y);
    split2(x2, h.z, l.z);
    split2(x3, h.w, l.w);
    size_t o = ((size_t)b * ESN_L + k0 + kk) * ESN_D + h0 + c4;
    *(ushort4*)&uh[o] = h;
    *(ushort4*)&ul[o] = l;
  }
}

// ---------- main GEMM: Z[b,p,n] = sum_h W[p,h] * Ut[b,n,h], hi/lo 3-product ----------
// 128x128 tile, BK=32, 4 waves (2x2), each wave 64x64 via 4x4 frags of 16x16x32.
// Staging via global_load_lds width=16 into LINEAR [128][32] tiles (row stride
// 64B => fragment ds_read_b128 is bank-balanced: 8 accesses on every bank =
// the 8-cycle minimum for 1024B; no pad/swizzle needed or allowed).
// 1-D grid + bijective XCD swizzle (1024 % 8 == 0): each XCD owns 2 complete
// p-panels -> W working set 4MB/XCD fits the private L2.
__global__ __launch_bounds__(256, 2) void k_esn_gemm(const unsigned short* __restrict__ Wh,
                                                     const unsigned short* __restrict__ Wl,
                                                     const unsigned short* __restrict__ Uh,
                                                     const unsigned short* __restrict__ Ul,
                                                     float* __restrict__ Z) {
  __shared__ __align__(16) unsigned short sm[4][128][32];  // Ah, Al, Bh, Bl (8KB each)

  const int vid = blockIdx.x;                      // 0..1023
  const int lg = ((vid & 7) << 7) | (vid >> 3);    // XCD-contiguous logical id
  const int p0 = (lg >> 6) * 128;                  // p-panel (slowest)
  const int b = (lg >> 2) & 15;                    // batch
  const int n0 = (lg & 3) * 128;                   // n-block (fastest)
  const int t = threadIdx.x;
  const int lane = t & 63;
  const int wid = t >> 6;
  const int wm = (wid >> 1) * 64;  // wave row offset in tile
  const int wn = (wid & 1) * 64;   // wave col offset in tile
  const int l15 = lane & 15;
  const int lg8 = (lane >> 4) * 8;

  // staging: wave wid stages 1KB chunks {2wid, 2wid+1} of each matrix.
  // chunk q covers rows q*16..q*16+15; lane l -> row q*16+(l>>2), ushort col (l&3)*8
  const int q0 = wid * 2;
  const int r0 = q0 * 16 + (lane >> 2);
  const int r1 = r0 + 16;
  const int sc = (lane & 3) * 8;

  const unsigned short* wh0 = Wh + (size_t)(p0 + r0) * ESN_D + sc;
  const unsigned short* wh1 = Wh + (size_t)(p0 + r1) * ESN_D + sc;
  const unsigned short* wl0 = Wl + (size_t)(p0 + r0) * ESN_D + sc;
  const unsigned short* wl1 = Wl + (size_t)(p0 + r1) * ESN_D + sc;
  const unsigned short* uh0 = Uh + ((size_t)b * ESN_L + n0 + r0) * ESN_D + sc;
  const unsigned short* uh1 = Uh + ((size_t)b * ESN_L + n0 + r1) * ESN_D + sc;
  const unsigned short* ul0 = Ul + ((size_t)b * ESN_L + n0 + r0) * ESN_D + sc;
  const unsigned short* ul1 = Ul + ((size_t)b * ESN_L + n0 + r1) * ESN_D + sc;

  unsigned short* dAh0 = &sm[0][q0 * 16][0];
  unsigned short* dAh1 = &sm[0][q0 * 16 + 16][0];
  unsigned short* dAl0 = &sm[1][q0 * 16][0];
  unsigned short* dAl1 = &sm[1][q0 * 16 + 16][0];
  unsigned short* dBh0 = &sm[2][q0 * 16][0];
  unsigned short* dBh1 = &sm[2][q0 * 16 + 16][0];
  unsigned short* dBl0 = &sm[3][q0 * 16][0];
  unsigned short* dBl1 = &sm[3][q0 * 16 + 16][0];

  f32x4 acc[4][4] = {};

  for (int h0 = 0; h0 < ESN_D; h0 += 32) {
    __syncthreads();  // all consumers of the previous tile are done
    gl2lds16(wh0 + h0, dAh0);
    gl2lds16(wh1 + h0, dAh1);
    gl2lds16(wl0 + h0, dAl0);
    gl2lds16(wl1 + h0, dAl1);
    gl2lds16(uh0 + h0, dBh0);
    gl2lds16(uh1 + h0, dBh1);
    gl2lds16(ul0 + h0, dBl0);
    gl2lds16(ul1 + h0, dBl1);
    __syncthreads();  // implicit vmcnt(0) drain before s_barrier -> tile visible

    bf16x8 ah[4], al[4], bh[4], bl[4];
#pragma unroll
    for (int i = 0; i < 4; ++i) {
      ah[i] = *(const bf16x8*)&sm[0][wm + i * 16 + l15][lg8];
      al[i] = *(const bf16x8*)&sm[1][wm + i * 16 + l15][lg8];
      bh[i] = *(const bf16x8*)&sm[2][wn + i * 16 + l15][lg8];
      bl[i] = *(const bf16x8*)&sm[3][wn + i * 16 + l15][lg8];
    }
#pragma unroll
    for (int i = 0; i < 4; ++i)
#pragma unroll
      for (int j = 0; j < 4; ++j) {
        acc[i][j] = __builtin_amdgcn_mfma_f32_16x16x32_bf16(ah[i], bh[j], acc[i][j], 0, 0, 0);
        acc[i][j] = __builtin_amdgcn_mfma_f32_16x16x32_bf16(ah[i], bl[j], acc[i][j], 0, 0, 0);
        acc[i][j] = __builtin_amdgcn_mfma_f32_16x16x32_bf16(al[i], bh[j], acc[i][j], 0, 0, 0);
      }
  }

// C/D layout (m89-verified): col = lane&15, row = (lane>>4)*4 + reg
#pragma unroll
  for (int i = 0; i < 4; ++i)
#pragma unroll
    for (int j = 0; j < 4; ++j) {
      const int rp = p0 + wm + i * 16 + (lane >> 4) * 4;
      const int cn = n0 + wn + j * 16 + l15;
      float* zp = &Z[((size_t)b * ESN_D + rp) * ESN_L + cn];
#pragma unroll
      for (int r = 0; r < 4; ++r) zp[(size_t)r * ESN_L] = acc[i][j][r];
    }
}

// ---------- fallback fp32 GEMM (no workspace needed): Z[b,p,n] = sum_h W[p,h]*U[b,h,n] ----------
__global__ __launch_bounds__(256) void k_gemm_f32(const float* __restrict__ W,
                                                  const float* __restrict__ U,
                                                  float* __restrict__ Z) {
  __shared__ float sA[16][65];  // [h][p]
  __shared__ float sB[16][65];  // [h][n]
  const int b = blockIdx.z, p0 = blockIdx.y * 64, n0 = blockIdx.x * 64;
  const int t = threadIdx.x;
  const int tx = t & 15, ty = t >> 4;
  float c[4][4] = {};
  for (int h0 = 0; h0 < ESN_D; h0 += 16) {
    __syncthreads();
#pragma unroll
    for (int i = 0; i < 4; ++i) {
      int e = t + i * 256;
      int ra = e >> 4, ca = e & 15;
      sA[ca][ra] = W[(size_t)(p0 + ra) * ESN_D + h0 + ca];
      int rb = e >> 6, cb = e & 63;
      sB[rb][cb] = U[((size_t)b * ESN_D + h0 + rb) * ESN_L + n0 + cb];
    }
    __syncthreads();
#pragma unroll
    for (int kk = 0; kk < 16; ++kk) {
      float a[4], bb[4];
#pragma unroll
      for (int i = 0; i < 4; ++i) a[i] = sA[kk][ty * 4 + i];
#pragma unroll
      for (int j = 0; j < 4; ++j) bb[j] = sB[kk][tx * 4 + j];
#pragma unroll
      for (int i = 0; i < 4; ++i)
#pragma unroll
        for (int j = 0; j < 4; ++j) c[i][j] += a[i] * bb[j];
    }
  }
#pragma unroll
  for (int i = 0; i < 4; ++i)
#pragma unroll
    for (int j = 0; j < 4; ++j)
      Z[((size_t)b * ESN_D + p0 + ty * 4 + i) * ESN_L + n0 + tx * 4 + j] = c[i][j];
}

// ---------- elementwise leaky-integrator scan, in place on Z (lr = 1) ----------
// tanh(x) = 1 - 2/(e^{2x}+1): saturates cleanly to +/-1 (inf-safe), ~1e-6 err.
__device__ __forceinline__ float fast_tanh(float x) {
  float e = __expf(2.0f * x);
  return 1.0f - __fdividef(2.0f, e + 1.0f);
}

// Coalesced scan: one wave per block, 64 rows/block, n walked in 32-col chunks.
// Global IO is 128B-coalesced float4 (8 lanes x 16B per row-slice); the serial
// per-row chain runs from registers after an LDS col-major transpose
// (tile[k][l]: bank (65k+l)%32 = (k+l)%32 -> 2-way = free). Single wave =>
// no barriers; waitcnts order the LDS phases. Next chunk prefetched to regs
// during the tanh chain.
__global__ __launch_bounds__(64) void k_scan(float* __restrict__ Z,
                                             const float* __restrict__ w_hh,
                                             const float* __restrict__ bias) {
  __shared__ float tile[32][65];  // [col-in-chunk][row] padded
  const int l = threadIdx.x;
  const size_t row0 = (size_t)blockIdx.x * 64;
  const int p = (int)((row0 + l) & (ESN_D - 1));
  const float dg = w_hh[(size_t)p * (ESN_D + 1)];  // diagonal element w_hh[p][p]
  const float bs = bias[p];
  const int lr = l >> 3;        // 0..7  (row sub-index for coalesced IO)
  const int lc = (l & 7) * 4;   // 0..28 (col within chunk)
  float* gb = Z + row0 * ESN_L;

  float4 gin[8];
#pragma unroll
  for (int i = 0; i < 8; ++i)
    gin[i] = *(const float4*)&gb[(size_t)(lr + i * 8) * ESN_L + lc];

  float x = 0.f;
  for (int c = 0; c < 16; ++c) {
    // scatter incoming chunk into col-major tile
#pragma unroll
    for (int i = 0; i < 8; ++i) {
      tile[lc + 0][lr + i * 8] = gin[i].x;
      tile[lc + 1][lr + i * 8] = gin[i].y;
      tile[lc + 2][lr + i * 8] = gin[i].z;
      tile[lc + 3][lr + i * 8] = gin[i].w;
    }
    // prefetch next chunk while the chain computes
    if (c + 1 < 16) {
      float* gn = gb + (size_t)(c + 1) * 32;
#pragma unroll
      for (int i = 0; i < 8; ++i)
        gin[i] = *(const float4*)&gn[(size_t)(lr + i * 8) * ESN_L + lc];
    }
    // own row -> registers (independent loads, batched), then serial chain
    float rv[32];
#pragma unroll
    for (int k = 0; k < 32; ++k) rv[k] = tile[k][l];
#pragma unroll
    for (int k = 0; k < 32; ++k) {
      x = fast_tanh(rv[k] + dg * x + bs);
      rv[k] = x;
    }
#pragma unroll
    for (int k = 0; k < 32; ++k) tile[k][l] = rv[k];
    // gather + coalesced store
    float* go = gb + (size_t)c * 32;
#pragma unroll
    for (int i = 0; i < 8; ++i) {
      float4 v;
      v.x = tile[lc + 0][lr + i * 8];
      v.y = tile[lc + 1][lr + i * 8];
      v.z = tile[lc + 2][lr + i * 8];
      v.w = tile[lc + 3][lr + i * 8];
      *(float4*)&go[(size_t)(lr + i * 8) * ESN_L + lc] = v;
    }
  }
}

extern "C" void kernel_launch(void* const* d_in, const int* in_sizes, int n_in, void* d_out,
                              int out_size, void* d_ws, size_t ws_size, hipStream_t stream) {
  const float* u = (const float*)d_in[0];
  const float* w_in = (const float*)d_in[1];
  const float* w_hh = (const float*)d_in[2];
  const float* bias = (const float*)d_in[3];
  float* Z = (float*)d_out;  // Z computed here, then scan updates in place

  const size_t nW = (size_t)ESN_D * ESN_D;
  const size_t nU = (size_t)ESN_B * ESN_L * ESN_D;
  const size_t needed = (2 * nW + 2 * nU) * sizeof(unsigned short);  // 80 MiB

  if (ws_size >= needed) {
    unsigned short* Wh = (unsigned short*)d_ws;
    unsigned short* Wl = Wh + nW;
    unsigned short* Uh = Wl + nW;
    unsigned short* Ul = Uh + nU;
    k_split_w<<<(int)(nW / 4 / 256), 256, 0, stream>>>(w_in, Wh, Wl);
    k_split_transpose_u<<<dim3(ESN_L / 64, ESN_D / 64, ESN_B), 256, 0, stream>>>(u, Uh, Ul);
    k_esn_gemm<<<1024, 256, 0, stream>>>(Wh, Wl, Uh, Ul, Z);
  } else {
    k_gemm_f32<<<dim3(ESN_L / 64, ESN_D / 64, ESN_B), 256, 0, stream>>>(w_in, u, Z);
  }
  k_scan<<<(ESN_B * ESN_D) / 64, 64, 0, stream>>>(Z, w_hh, bias);
}

// Round 4
// 330.931 us; speedup vs baseline: 1.2769x; 1.2201x over previous
//
#include <hip/hip_runtime.h>

#define ESN_B 16
#define ESN_D 2048
#define ESN_L 512

typedef __attribute__((ext_vector_type(8))) short bf16x8;
typedef __attribute__((ext_vector_type(4))) float f32x4;

typedef unsigned int __attribute__((address_space(1))) as1_u32;
typedef unsigned int __attribute__((address_space(3))) as3_u32;

__device__ __forceinline__ void gl2lds16(const void* g, void* l) {
  // async global->LDS, 16B per lane; LDS dest = wave-uniform base + lane*16
  __builtin_amdgcn_global_load_lds((const as1_u32*)g, (as3_u32*)l, 16, 0, 0);
}

__device__ __forceinline__ unsigned short f2bf_rne(float x) {
  unsigned int u = __float_as_uint(x);
  unsigned int r = (u + 0x7FFFu + ((u >> 16) & 1u)) >> 16;
  return (unsigned short)r;
}
__device__ __forceinline__ float bf2f(unsigned short h) {
  return __uint_as_float(((unsigned int)h) << 16);
}
__device__ __forceinline__ void split2(float x, unsigned short& h, unsigned short& l) {
  h = f2bf_rne(x);
  l = f2bf_rne(x - bf2f(h));
}

// ---------- split w_in (fp32 [D][D]) into hi/lo bf16, same layout ----------
__global__ __launch_bounds__(256) void k_split_w(const float* __restrict__ w,
                                                 unsigned short* __restrict__ wh,
                                                 unsigned short* __restrict__ wl) {
  int i = blockIdx.x * 256 + threadIdx.x;  // grid sized exactly: D*D/4 elements
  float4 v = ((const float4*)w)[i];
  ushort4 h, l;
  split2(v.x, h.x, l.x);
  split2(v.y, h.y, l.y);
  split2(v.z, h.z, l.z);
  split2(v.w, h.w, l.w);
  ((ushort4*)wh)[i] = h;
  ((ushort4*)wl)[i] = l;
}

// ---------- split + transpose u: [B][D][L] fp32 -> [B][L][D] bf16 hi/lo ----------
__global__ __launch_bounds__(256) void k_split_transpose_u(const float* __restrict__ u,
                                                           unsigned short* __restrict__ uh,
                                                           unsigned short* __restrict__ ul) {
  __shared__ float tile[64][65];
  const int b = blockIdx.z;
  const int h0 = blockIdx.y * 64;
  const int k0 = blockIdx.x * 64;
  const int t = threadIdx.x;
  const int r = t >> 4;         // 0..15
  const int c4 = (t & 15) * 4;  // 0..60
#pragma unroll
  for (int i = 0; i < 4; ++i) {
    int hh = r + i * 16;
    float4 v = *(const float4*)&u[((size_t)b * ESN_D + h0 + hh) * ESN_L + k0 + c4];
    tile[hh][c4 + 0] = v.x;
    tile[hh][c4 + 1] = v.y;
    tile[hh][c4 + 2] = v.z;
    tile[hh][c4 + 3] = v.w;
  }
  __syncthreads();
#pragma unroll
  for (int i = 0; i < 4; ++i) {
    int kk = r + i * 16;
    float x0 = tile[c4 + 0][kk], x1 = tile[c4 + 1][kk];
    float x2 = tile[c4 + 2][kk], x3 = tile[c4 + 3][kk];
    ushort4 h, l;
    split2(x0, h.x, l.x);
    split2(x1, h.y, l.y);
    split2(x2, h.z, l.z);
    split2(x3, h.w, l.w);
    size_t o = ((size_t)b * ESN_L + k0 + kk) * ESN_D + h0 + c4;
    *(ushort4*)&uh[o] = h;
    *(ushort4*)&ul[o] = l;
  }
}

// ---------- main GEMM: Z[b,p,n] = sum_h W[p,h] * Ut[b,n,h], hi/lo 3-product ----------
// 256x256 tile, BK=32, 8 waves (2M x 4N), 8-phase-style schedule (T3+T4+T5):
// per K-tile 4 phases of {ds_read quadrant frags || 2 gl2lds stage calls for
// tile t+1 -> advisory s_barrier -> lgkmcnt(0) -> setprio(1) 24 MFMA setprio(0)
// -> barrier}. Only the K-tile boundary __syncthreads() is correctness-critical;
// its implicit vmcnt(0) drain is exactly the counted wait (8 in-flight stage
// calls, issued 1-4 phases earlier = latency hidden under MFMA).
// LDS: 2 dbuf x 4 matrices (Ah,Al,Bh,Bl) x [256][32] = 128 KB, row stride 64B
// -> fragment ds_read_b128 is 2 lanes/bank = free (no swizzle needed).
__global__ __launch_bounds__(512, 2) void k_esn_gemm(const unsigned short* __restrict__ Wh,
                                                     const unsigned short* __restrict__ Wl,
                                                     const unsigned short* __restrict__ Uh,
                                                     const unsigned short* __restrict__ Ul,
                                                     float* __restrict__ Z) {
  __shared__ __align__(16) unsigned short sm[2][4][256][32];  // [buf][mtx][row][k]

  const int b = blockIdx.z;
  const int p0 = blockIdx.y * 256;
  const int n0 = blockIdx.x * 256;
  const int t = threadIdx.x;
  const int lane = t & 63;
  const int wid = t >> 6;
  const int wr = wid >> 2;  // 0..1: wave owns rows wr*128..+127
  const int wc = wid & 3;   // 0..3: wave owns cols wc*64..+63
  const int l15 = lane & 15;
  const int lg8 = (lane >> 4) * 8;

  // staging role: wave wid stages matrix mtx (0=Ah,1=Al,2=Bh,3=Bl), half hf.
  // 8 calls/K-tile of 1KB each: rows hf*128 + c*16 .. +15, 4 lanes per row.
  const int mtx = wid & 3;
  const int hf = wid >> 2;
  const unsigned short* gb;
  {
    const unsigned short* mat = (mtx == 0) ? Wh : (mtx == 1) ? Wl : (mtx == 2) ? Uh : Ul;
    const int rowbase = ((mtx < 2) ? p0 : (b * ESN_L + n0)) + hf * 128 + (lane >> 2);
    gb = mat + (size_t)rowbase * ESN_D + (lane & 3) * 8;
  }

  f32x4 acc[8][4] = {};

  // prologue: stage K-tile 0 into buf 0
#pragma unroll
  for (int c = 0; c < 8; ++c)
    gl2lds16(gb + (size_t)(c * 16) * ESN_D, &sm[0][mtx][hf * 128 + c * 16][0]);
  __syncthreads();

  int cur = 0;
#pragma unroll 2
  for (int kt = 0; kt < 64; ++kt) {
    const int h1 = (kt + 1) * 32;
    bf16x8 bh[4], bl[4];
#pragma unroll
    for (int q = 0; q < 4; ++q) {
      const int m0 = 2 * q, m1 = 2 * q + 1;
      // ds-load this quadrant's A frags (+ all B frags at q==0)
      bf16x8 a0h = *(const bf16x8*)&sm[cur][0][wr * 128 + m0 * 16 + l15][lg8];
      bf16x8 a1h = *(const bf16x8*)&sm[cur][0][wr * 128 + m1 * 16 + l15][lg8];
      bf16x8 a0l = *(const bf16x8*)&sm[cur][1][wr * 128 + m0 * 16 + l15][lg8];
      bf16x8 a1l = *(const bf16x8*)&sm[cur][1][wr * 128 + m1 * 16 + l15][lg8];
      if (q == 0) {
#pragma unroll
        for (int nj = 0; nj < 4; ++nj) {
          bh[nj] = *(const bf16x8*)&sm[cur][2][wc * 64 + nj * 16 + l15][lg8];
          bl[nj] = *(const bf16x8*)&sm[cur][3][wc * 64 + nj * 16 + l15][lg8];
        }
      }
      // stage 2 chunks of K-tile kt+1 into the other buffer
      if (kt < 63) {
        gl2lds16(gb + (size_t)(m0 * 16) * ESN_D + h1, &sm[cur ^ 1][mtx][hf * 128 + m0 * 16][0]);
        gl2lds16(gb + (size_t)(m1 * 16) * ESN_D + h1, &sm[cur ^ 1][mtx][hf * 128 + m1 * 16][0]);
      }
      __builtin_amdgcn_s_barrier();  // advisory: align waves' MFMA clusters
      asm volatile("s_waitcnt lgkmcnt(0)");
      __builtin_amdgcn_sched_barrier(0);
      __builtin_amdgcn_s_setprio(1);
#pragma unroll
      for (int nj = 0; nj < 4; ++nj) {
        acc[m0][nj] = __builtin_amdgcn_mfma_f32_16x16x32_bf16(a0h, bh[nj], acc[m0][nj], 0, 0, 0);
        acc[m0][nj] = __builtin_amdgcn_mfma_f32_16x16x32_bf16(a0h, bl[nj], acc[m0][nj], 0, 0, 0);
        acc[m0][nj] = __builtin_amdgcn_mfma_f32_16x16x32_bf16(a0l, bh[nj], acc[m0][nj], 0, 0, 0);
        acc[m1][nj] = __builtin_amdgcn_mfma_f32_16x16x32_bf16(a1h, bh[nj], acc[m1][nj], 0, 0, 0);
        acc[m1][nj] = __builtin_amdgcn_mfma_f32_16x16x32_bf16(a1h, bl[nj], acc[m1][nj], 0, 0, 0);
        acc[m1][nj] = __builtin_amdgcn_mfma_f32_16x16x32_bf16(a1l, bh[nj], acc[m1][nj], 0, 0, 0);
      }
      __builtin_amdgcn_s_setprio(0);
      __builtin_amdgcn_sched_barrier(0);
      if (q < 3) __builtin_amdgcn_s_barrier();
    }
    // K-tile boundary: implicit vmcnt(0)+lgkmcnt(0) drain + barrier. The 8
    // stage calls for kt+1 were issued 1-4 phases ago -> mostly complete.
    __syncthreads();
    cur ^= 1;
  }

// C/D layout (m89-verified): col = lane&15, row = (lane>>4)*4 + reg
#pragma unroll
  for (int i = 0; i < 8; ++i)
#pragma unroll
    for (int j = 0; j < 4; ++j) {
      const int rp = p0 + wr * 128 + i * 16 + (lane >> 4) * 4;
      const int cn = n0 + wc * 64 + j * 16 + l15;
      float* zp = &Z[((size_t)b * ESN_D + rp) * ESN_L + cn];
#pragma unroll
      for (int r = 0; r < 4; ++r) zp[(size_t)r * ESN_L] = acc[i][j][r];
    }
}

// ---------- fallback fp32 GEMM (no workspace needed): Z[b,p,n] = sum_h W[p,h]*U[b,h,n] ----------
__global__ __launch_bounds__(256) void k_gemm_f32(const float* __restrict__ W,
                                                  const float* __restrict__ U,
                                                  float* __restrict__ Z) {
  __shared__ float sA[16][65];  // [h][p]
  __shared__ float sB[16][65];  // [h][n]
  const int b = blockIdx.z, p0 = blockIdx.y * 64, n0 = blockIdx.x * 64;
  const int t = threadIdx.x;
  const int tx = t & 15, ty = t >> 4;
  float c[4][4] = {};
  for (int h0 = 0; h0 < ESN_D; h0 += 16) {
    __syncthreads();
#pragma unroll
    for (int i = 0; i < 4; ++i) {
      int e = t + i * 256;
      int ra = e >> 4, ca = e & 15;
      sA[ca][ra] = W[(size_t)(p0 + ra) * ESN_D + h0 + ca];
      int rb = e >> 6, cb = e & 63;
      sB[rb][cb] = U[((size_t)b * ESN_D + h0 + rb) * ESN_L + n0 + cb];
    }
    __syncthreads();
#pragma unroll
    for (int kk = 0; kk < 16; ++kk) {
      float a[4], bb[4];
#pragma unroll
      for (int i = 0; i < 4; ++i) a[i] = sA[kk][ty * 4 + i];
#pragma unroll
      for (int j = 0; j < 4; ++j) bb[j] = sB[kk][tx * 4 + j];
#pragma unroll
      for (int i = 0; i < 4; ++i)
#pragma unroll
        for (int j = 0; j < 4; ++j) c[i][j] += a[i] * bb[j];
    }
  }
#pragma unroll
  for (int i = 0; i < 4; ++i)
#pragma unroll
    for (int j = 0; j < 4; ++j)
      Z[((size_t)b * ESN_D + p0 + ty * 4 + i) * ESN_L + n0 + tx * 4 + j] = c[i][j];
}

// ---------- elementwise leaky-integrator scan, in place on Z (lr = 1) ----------
// tanh(x) = 1 - 2/(e^{2x}+1): saturates cleanly to +/-1 (inf-safe), ~1e-6 err.
__device__ __forceinline__ float fast_tanh(float x) {
  float e = __expf(2.0f * x);
  return 1.0f - __fdividef(2.0f, e + 1.0f);
}

// Coalesced scan: one wave per block, 64 rows/block, n walked in 32-col chunks.
// Global IO is 128B-coalesced float4; serial per-row chain runs from registers
// after an LDS col-major transpose (bank (k+l)%32 -> 2-way = free). Single
// wave => no barriers. Next chunk prefetched to regs during the tanh chain.
__global__ __launch_bounds__(64) void k_scan(float* __restrict__ Z,
                                             const float* __restrict__ w_hh,
                                             const float* __restrict__ bias) {
  __shared__ float tile[32][65];  // [col-in-chunk][row] padded
  const int l = threadIdx.x;
  const size_t row0 = (size_t)blockIdx.x * 64;
  const int p = (int)((row0 + l) & (ESN_D - 1));
  const float dg = w_hh[(size_t)p * (ESN_D + 1)];  // diagonal element w_hh[p][p]
  const float bs = bias[p];
  const int lr = l >> 3;       // 0..7  (row sub-index for coalesced IO)
  const int lc = (l & 7) * 4;  // 0..28 (col within chunk)
  float* gb = Z + row0 * ESN_L;

  float4 gin[8];
#pragma unroll
  for (int i = 0; i < 8; ++i)
    gin[i] = *(const float4*)&gb[(size_t)(lr + i * 8) * ESN_L + lc];

  float x = 0.f;
  for (int c = 0; c < 16; ++c) {
    // scatter incoming chunk into col-major tile
#pragma unroll
    for (int i = 0; i < 8; ++i) {
      tile[lc + 0][lr + i * 8] = gin[i].x;
      tile[lc + 1][lr + i * 8] = gin[i].y;
      tile[lc + 2][lr + i * 8] = gin[i].z;
      tile[lc + 3][lr + i * 8] = gin[i].w;
    }
    // prefetch next chunk while the chain computes
    if (c + 1 < 16) {
      float* gn = gb + (size_t)(c + 1) * 32;
#pragma unroll
      for (int i = 0; i < 8; ++i)
        gin[i] = *(const float4*)&gn[(size_t)(lr + i * 8) * ESN_L + lc];
    }
    // own row -> registers, then serial chain
    float rv[32];
#pragma unroll
    for (int k = 0; k < 32; ++k) rv[k] = tile[k][l];
#pragma unroll
    for (int k = 0; k < 32; ++k) {
      x = fast_tanh(rv[k] + dg * x + bs);
      rv[k] = x;
    }
#pragma unroll
    for (int k = 0; k < 32; ++k) tile[k][l] = rv[k];
    // gather + coalesced store
    float* go = gb + (size_t)c * 32;
#pragma unroll
    for (int i = 0; i < 8; ++i) {
      float4 v;
      v.x = tile[lc + 0][lr + i * 8];
      v.y = tile[lc + 1][lr + i * 8];
      v.z = tile[lc + 2][lr + i * 8];
      v.w = tile[lc + 3][lr + i * 8];
      *(float4*)&go[(size_t)(lr + i * 8) * ESN_L + lc] = v;
    }
  }
}

extern "C" void kernel_launch(void* const* d_in, const int* in_sizes, int n_in, void* d_out,
                              int out_size, void* d_ws, size_t ws_size, hipStream_t stream) {
  const float* u = (const float*)d_in[0];
  const float* w_in = (const float*)d_in[1];
  const float* w_hh = (const float*)d_in[2];
  const float* bias = (const float*)d_in[3];
  float* Z = (float*)d_out;  // Z computed here, then scan updates in place

  const size_t nW = (size_t)ESN_D * ESN_D;
  const size_t nU = (size_t)ESN_B * ESN_L * ESN_D;
  const size_t needed = (2 * nW + 2 * nU) * sizeof(unsigned short);  // 80 MiB

  if (ws_size >= needed) {
    unsigned short* Wh = (unsigned short*)d_ws;
    unsigned short* Wl = Wh + nW;
    unsigned short* Uh = Wl + nW;
    unsigned short* Ul = Uh + nU;
    k_split_w<<<(int)(nW / 4 / 256), 256, 0, stream>>>(w_in, Wh, Wl);
    k_split_transpose_u<<<dim3(ESN_L / 64, ESN_D / 64, ESN_B), 256, 0, stream>>>(u, Uh, Ul);
    // grid: x=n (2), y=p (8), z=b (16). Linear id = n + 2p + 16b; with
    // round-robin XCD = id%8, each XCD holds a fixed (p-pair, n-half):
    // W slice 4MB -> L2-resident; U refetches absorbed by L3.
    k_esn_gemm<<<dim3(ESN_L / 256, ESN_D / 256, ESN_B), 512, 0, stream>>>(Wh, Wl, Uh, Ul, Z);
  } else {
    k_gemm_f32<<<dim3(ESN_L / 64, ESN_D / 64, ESN_B), 256, 0, stream>>>(w_in, u, Z);
  }
  k_scan<<<(ESN_B * ESN_D) / 64, 64, 0, stream>>>(Z, w_hh, bias);
}